// Round 1
// baseline (115.026 us; speedup 1.0000x reference)
//
#include <hip/hip_runtime.h>
#include <math.h>

#define BLOCK 256
#define PPT 4            // owned points per thread -> 1024 points per block
#define NCHUNK 16        // opposing dimension split into 16 chunks of 512
#define CHUNK_MAX 512

// ---- order-preserving float <-> uint key (works for negatives) ----
__device__ __forceinline__ unsigned f2key(float f) {
    unsigned b = __float_as_uint(f);
    return b ^ ((b & 0x80000000u) ? 0xFFFFFFFFu : 0x80000000u);
}
__device__ __forceinline__ float key2f(unsigned k) {
    unsigned b = k ^ ((k & 0x80000000u) ? 0x80000000u : 0xFFFFFFFFu);
    return __uint_as_float(b);
}

// For each owned point p in A, min over a chunk of B's points of (b^2 - 2 a.b).
// dist(p) = a^2 + min_u  (a^2 added in finalize).
// wsmin layout: [dir0: B*N keys][dir1: B*M keys]
__global__ __launch_bounds__(BLOCK) void chamfer_min_kernel(
    const float* __restrict__ arr1, const float* __restrict__ arr2,
    int Bb, int N, int M, unsigned* __restrict__ wsmin)
{
    const int dir = blockIdx.z;
    const float* Aptr = dir ? arr2 : arr1;   // owned points
    const float* Bptr = dir ? arr1 : arr2;   // scanned points
    const int nA = dir ? M : N;
    const int nB = dir ? N : M;
    unsigned* wmin = wsmin + (dir ? (size_t)Bb * N : 0);

    const int clen = nB / NCHUNK;                    // 512
    const int a_start = blockIdx.x * (BLOCK * PPT);  // flat index into [Bb*nA)
    const int batch   = a_start / nA;

    __shared__ float4 sb[CHUNK_MAX];

    // Stage chunk of scanned points, pre-scaled: (-2x, -2y, -2z, |b|^2)
    {
        const float* bbase = Bptr + ((size_t)batch * nB + (size_t)blockIdx.y * clen) * 3;
        for (int i = threadIdx.x; i < clen; i += BLOCK) {
            float x = bbase[i * 3 + 0];
            float y = bbase[i * 3 + 1];
            float z = bbase[i * 3 + 2];
            sb[i] = make_float4(-2.0f * x, -2.0f * y, -2.0f * z,
                                __builtin_fmaf(x, x, __builtin_fmaf(y, y, z * z)));
        }
    }
    __syncthreads();

    // Load owned points into registers
    float ax[PPT], ay[PPT], az[PPT], mn[PPT];
    const float* abase = Aptr + (size_t)a_start * 3;
#pragma unroll
    for (int k = 0; k < PPT; ++k) {
        int idx = threadIdx.x + k * BLOCK;
        ax[k] = abase[idx * 3 + 0];
        ay[k] = abase[idx * 3 + 1];
        az[k] = abase[idx * 3 + 2];
        mn[k] = __builtin_inff();
    }

    // Inner scan: 4 VALU per pair (3 fma + min), LDS read is a wave-uniform broadcast
#pragma unroll 4
    for (int j = 0; j < clen; ++j) {
        float4 b = sb[j];
#pragma unroll
        for (int k = 0; k < PPT; ++k) {
            float u = __builtin_fmaf(b.z, az[k], b.w);
            u = __builtin_fmaf(b.y, ay[k], u);
            u = __builtin_fmaf(b.x, ax[k], u);
            mn[k] = fminf(mn[k], u);
        }
    }

    // Combine partial mins across chunks
#pragma unroll
    for (int k = 0; k < PPT; ++k) {
        atomicMin(&wmin[a_start + threadIdx.x + k * BLOCK], f2key(mn[k]));
    }
}

__global__ __launch_bounds__(1024) void chamfer_finalize_kernel(
    const float* __restrict__ arr1, const float* __restrict__ arr2,
    const unsigned* __restrict__ wsmin, int Bb, int N, int M,
    float* __restrict__ out)
{
    __shared__ float red[1024];
    const int tid = threadIdx.x;
    const int BN = Bb * N, BM = Bb * M;

    float s1 = 0.0f;
    for (int i = tid; i < BN; i += 1024) {
        float x = arr1[i * 3 + 0], y = arr1[i * 3 + 1], z = arr1[i * 3 + 2];
        float a2 = __builtin_fmaf(x, x, __builtin_fmaf(y, y, z * z));
        s1 += a2 + key2f(wsmin[i]);
    }
    float s2 = 0.0f;
    for (int i = tid; i < BM; i += 1024) {
        float x = arr2[i * 3 + 0], y = arr2[i * 3 + 1], z = arr2[i * 3 + 2];
        float b2 = __builtin_fmaf(x, x, __builtin_fmaf(y, y, z * z));
        s2 += b2 + key2f(wsmin[BN + i]);
    }

    red[tid] = s1 / (float)BN + s2 / (float)BM;
    __syncthreads();
    for (int off = 512; off > 0; off >>= 1) {
        if (tid < off) red[tid] += red[tid + off];
        __syncthreads();
    }
    if (tid == 0) out[0] = red[0];
}

extern "C" void kernel_launch(void* const* d_in, const int* in_sizes, int n_in,
                              void* d_out, int out_size, void* d_ws, size_t ws_size,
                              hipStream_t stream)
{
    const float* arr1 = (const float*)d_in[0];
    const float* arr2 = (const float*)d_in[1];
    float* out = (float*)d_out;

    const int Bb = 4;
    const int N = in_sizes[0] / (Bb * 3);   // 8192
    const int M = in_sizes[1] / (Bb * 3);   // 8192

    unsigned* wsmin = (unsigned*)d_ws;
    const size_t nkeys = (size_t)Bb * N + (size_t)Bb * M;

    // Init min-keys to 0xFFFFFFFF (max key)
    hipMemsetAsync(wsmin, 0xFF, nkeys * sizeof(unsigned), stream);

    dim3 grid((Bb * N) / (BLOCK * PPT), NCHUNK, 2);   // (32, 16, 2)
    chamfer_min_kernel<<<grid, BLOCK, 0, stream>>>(arr1, arr2, Bb, N, M, wsmin);

    chamfer_finalize_kernel<<<1, 1024, 0, stream>>>(arr1, arr2, wsmin, Bb, N, M, out);
}